// Round 14
// baseline (35.946 us; speedup 1.0000x reference)
//
#include <hip/hip_runtime.h>

#define NBLK 1024
#define SBAT 256
#define SBLK 8

#define CL 24               // outputs per chunk (43 chunks, last=16)
#define HW 8                // warm-up steps (even; ||C||^8 ~ 1e-6, invisible)
#define W  (CL + HW)        // 32 window steps (even)
#define NJ (W / 2)          // 16 composed (pair) steps
#define NCH 43              // ceil(NBLK / CL)
#define P  2                // batches per block
#define NSYS (W * P)        // 64 systems per block
#define THREADS (NSYS * 4)  // 256 threads = 4 waves

// Broadcast lane Q (0..3) of each 4-lane quad to all 4: pure VALU DPP.
template <int Q>
__device__ __forceinline__ float bc4(float x) {
  return __int_as_float(__builtin_amdgcn_update_dpp(
      0, __float_as_int(x), Q * 0x55, 0xF, 0xF, true));
}

// Fused solver with one parallel-cyclic-reduction level.
//   GJ phase (256 thr): quad-DPP Gauss-Jordan -> C_i = A_i^{-1}B_{i-1},
//     d_i = A_i^{-1}v_i in LDS (C_0 = 0).
//   Compose phase (256 thr): pairwise composition overwrites ODD slots:
//     C' = -C_o C_e, d' = d_o - C_o d_e  (one PCR level; halves the chain).
//   Tail (8 lanes, 2 chains x 4 lanes): 16 composed steps
//     x_odd = d' - C' x_prev_odd; broadcast via quad_perm DPP (no DS on the
//     critical path; C'/d' prefetched). Odd x -> out and Xs.
//   Post phase (256 thr): even outputs x_e = d_e - C_e x_prev_odd from Xs.
// Chunked time-parallelism as before: HW warm-up steps from x=0 absorb the
// unknown carry (chunk 0 exact).
__global__ __launch_bounds__(THREADS) void pcr_fused(
    const float* __restrict__ A, const float* __restrict__ B,
    const float* __restrict__ v, float* __restrict__ out) {
  __shared__ float Cs[NSYS * 64];     // 16 KB; chunk k of GJ-thread t at (k*256+t)*16B
  __shared__ float Ds[NSYS * 8];      // 2 KB
  __shared__ float Xs[P][NJ + 1][8];  // odd-x history for the post phase

  const int t  = threadIdx.x;
  const int ch = blockIdx.x >> 7;           // chunk 0..42
  const int b0 = (blockIdx.x & 127) * P;    // batch panel origin
  const int i_first = (ch > 0) ? (ch * CL - HW) : 0;
  const int o_lo = ch * CL;
  const int o_hi = (o_lo + CL > NBLK) ? NBLK : (o_lo + CL);

  {  // ---------------- GJ phase ----------------
    const int s_local = t >> 2;              // system 0..63
    const int l = t & 3;                     // lane-in-quad: owns rows 2l,2l+1
    const int iw = s_local >> 1, q = s_local & 1;
    int i = i_first + iw;
    i = (i > NBLK - 1) ? (NBLK - 1) : i;     // clamp top window overhang
    const int b = b0 + q;
    const long sysid = (long)i * SBAT + b;

    float a[2][8], c[2][8], vv[2];
    {
      const float4* A4 = (const float4*)(A + sysid * 64 + l * 16);
      #pragma unroll
      for (int k = 0; k < 4; ++k) {
        const float4 x4 = A4[k];
        const int m = k >> 1, c0 = (k & 1) * 4;
        a[m][c0+0]=x4.x; a[m][c0+1]=x4.y; a[m][c0+2]=x4.z; a[m][c0+3]=x4.w;
      }
    }
    if (i > 0) {
      const float4* B4 = (const float4*)(B + (sysid - SBAT) * 64 + l * 16);
      #pragma unroll
      for (int k = 0; k < 4; ++k) {
        const float4 x4 = B4[k];
        const int m = k >> 1, c0 = (k & 1) * 4;
        c[m][c0+0]=x4.x; c[m][c0+1]=x4.y; c[m][c0+2]=x4.z; c[m][c0+3]=x4.w;
      }
    } else {
      #pragma unroll
      for (int m = 0; m < 2; ++m)
        #pragma unroll
        for (int j = 0; j < 8; ++j) c[m][j] = 0.f;
    }
    {
      const float2 x2 = *(const float2*)(v + (long)b * (NBLK * SBLK) + i * SBLK + 2 * l);
      vv[0] = x2.x; vv[1] = x2.y;
    }

#define GJSTEP(K)                                                       \
    {                                                                   \
      constexpr int ol = (K) >> 1;                                      \
      constexpr int mp = (K) & 1;                                       \
      const bool mine = (l == ol);                                      \
      const float invp = 1.0f / a[mp][(K)];                             \
      const float s = mine ? invp : 1.0f;                               \
      _Pragma("unroll")                                                 \
      for (int j = (K) + 1; j < 8; ++j) a[mp][j] *= s;                  \
      _Pragma("unroll")                                                 \
      for (int j = 0; j < 8; ++j) c[mp][j] *= s;                        \
      vv[mp] *= s;                                                      \
      float pa[8], pc[8], pv;                                           \
      _Pragma("unroll")                                                 \
      for (int j = (K) + 1; j < 8; ++j) pa[j] = bc4<ol>(a[mp][j]);      \
      _Pragma("unroll")                                                 \
      for (int j = 0; j < 8; ++j) pc[j] = bc4<ol>(c[mp][j]);            \
      pv = bc4<ol>(vv[mp]);                                             \
      _Pragma("unroll")                                                 \
      for (int m = 0; m < 2; ++m) {                                     \
        float f = a[m][(K)];                                            \
        if (m == mp) f = mine ? 0.0f : f;                               \
        _Pragma("unroll")                                               \
        for (int j = (K) + 1; j < 8; ++j)                               \
          a[m][j] = fmaf(-f, pa[j], a[m][j]);                           \
        _Pragma("unroll")                                               \
        for (int j = 0; j < 8; ++j)                                     \
          c[m][j] = fmaf(-f, pc[j], c[m][j]);                           \
        vv[m] = fmaf(-f, pv, vv[m]);                                    \
      }                                                                 \
    }

    GJSTEP(0) GJSTEP(1) GJSTEP(2) GJSTEP(3)
    GJSTEP(4) GJSTEP(5) GJSTEP(6) GJSTEP(7)
#undef GJSTEP

    {  // C rows -> LDS (chunk-major: wave-contiguous b128 stores)
      #pragma unroll
      for (int k = 0; k < 4; ++k) {
        const int m = k >> 1, c0 = (k & 1) * 4;
        *(float4*)((char*)Cs + ((k * THREADS + t) * 16)) =
            make_float4(c[m][c0+0], c[m][c0+1], c[m][c0+2], c[m][c0+3]);
      }
      *(float2*)((char*)Ds + t * 8) = make_float2(vv[0], vv[1]);
    }
  }

  __syncthreads();

  {  // ---------------- compose phase (one PCR level) ----------------
    // pair pj: time-pair j, batch q; systems s_e = 4j+q, s_o = 4j+2+q.
    // thread r of the pair: row r of C' = -C_o C_e, comp r of d' = d_o - C_o d_e.
    const int pj = t >> 3, r = t & 7;
    const int j = pj >> 1, q = pj & 1;
    const int s_e = 4 * j + q, s_o = s_e + 2;
    const int to = 4 * s_o + (r >> 1);
    const int h0 = 2 * (r & 1);

    float co[8];
    {
      const float4 lo = *(const float4*)((const char*)Cs + (((h0    ) * THREADS + to) * 16));
      const float4 hi = *(const float4*)((const char*)Cs + (((h0 + 1) * THREADS + to) * 16));
      co[0]=lo.x; co[1]=lo.y; co[2]=lo.z; co[3]=lo.w;
      co[4]=hi.x; co[5]=hi.y; co[6]=hi.z; co[7]=hi.w;
    }
    float u = Ds[to * 2 + (r & 1)];
    float T[8];
    #pragma unroll
    for (int k = 0; k < 8; ++k) T[k] = 0.f;
    #pragma unroll
    for (int m = 0; m < 8; ++m) {
      const int te = 4 * s_e + (m >> 1);
      const int he = 2 * (m & 1);
      const float4 lo = *(const float4*)((const char*)Cs + (((he    ) * THREADS + te) * 16));
      const float4 hi = *(const float4*)((const char*)Cs + (((he + 1) * THREADS + te) * 16));
      const float de = Ds[te * 2 + (m & 1)];
      const float cm = co[m];
      T[0] = fmaf(-cm, lo.x, T[0]); T[1] = fmaf(-cm, lo.y, T[1]);
      T[2] = fmaf(-cm, lo.z, T[2]); T[3] = fmaf(-cm, lo.w, T[3]);
      T[4] = fmaf(-cm, hi.x, T[4]); T[5] = fmaf(-cm, hi.y, T[5]);
      T[6] = fmaf(-cm, hi.z, T[6]); T[7] = fmaf(-cm, hi.w, T[7]);
      u = fmaf(-cm, de, u);
    }
    // overwrite the ODD slot in place (only this thread touches row r of s_o)
    *(float4*)((char*)Cs + (((h0    ) * THREADS + to) * 16)) = make_float4(T[0], T[1], T[2], T[3]);
    *(float4*)((char*)Cs + (((h0 + 1) * THREADS + to) * 16)) = make_float4(T[4], T[5], T[6], T[7]);
    Ds[to * 2 + (r & 1)] = u;
  }

  __syncthreads();

  if (t < 8) {  // ---------------- tail: 2 chains x 4 lanes ----------------
    const int q = t >> 2, lq = t & 3;   // chain, lane-in-quad (rows 2lq,2lq+1)
    float* const ob = out + (long)(b0 + q) * (NBLK * SBLK);

    *(float2*)&Xs[q][0][2 * lq] = make_float2(0.f, 0.f);

    float xp[8];
    #pragma unroll
    for (int m = 0; m < 8; ++m) xp[m] = 0.f;

#define CLOAD(J, R0L, R0H, R1L, R1H, DD)                                  \
    {                                                                     \
      const int tt = 4 * (4 * (J) + 2 + q) + lq;                          \
      R0L = *(const float4*)((const char*)Cs + ((0 * THREADS + tt) * 16)); \
      R0H = *(const float4*)((const char*)Cs + ((1 * THREADS + tt) * 16)); \
      R1L = *(const float4*)((const char*)Cs + ((2 * THREADS + tt) * 16)); \
      R1H = *(const float4*)((const char*)Cs + ((3 * THREADS + tt) * 16)); \
      DD  = *(const float2*)&Ds[tt * 2];                                  \
    }
#define TSTEP(R0L, R0H, R1L, R1H, DD, J)                                  \
    {                                                                     \
      float xo0 = DD.x, xo1 = DD.y;                                       \
      xo0 = fmaf(-R0L.x, xp[0], xo0); xo1 = fmaf(-R1L.x, xp[0], xo1);     \
      xo0 = fmaf(-R0L.y, xp[1], xo0); xo1 = fmaf(-R1L.y, xp[1], xo1);     \
      xo0 = fmaf(-R0L.z, xp[2], xo0); xo1 = fmaf(-R1L.z, xp[2], xo1);     \
      xo0 = fmaf(-R0L.w, xp[3], xo0); xo1 = fmaf(-R1L.w, xp[3], xo1);     \
      xo0 = fmaf(-R0H.x, xp[4], xo0); xo1 = fmaf(-R1H.x, xp[4], xo1);     \
      xo0 = fmaf(-R0H.y, xp[5], xo0); xo1 = fmaf(-R1H.y, xp[5], xo1);     \
      xo0 = fmaf(-R0H.z, xp[6], xo0); xo1 = fmaf(-R1H.z, xp[6], xo1);     \
      xo0 = fmaf(-R0H.w, xp[7], xo0); xo1 = fmaf(-R1H.w, xp[7], xo1);     \
      xp[0] = bc4<0>(xo0); xp[1] = bc4<0>(xo1);                           \
      xp[2] = bc4<1>(xo0); xp[3] = bc4<1>(xo1);                           \
      xp[4] = bc4<2>(xo0); xp[5] = bc4<2>(xo1);                           \
      xp[6] = bc4<3>(xo0); xp[7] = bc4<3>(xo1);                           \
      const int ia = i_first + 2 * (J) + 1;                               \
      if (ia >= o_lo && ia < o_hi)                                        \
        *(float2*)&ob[ia * 8 + 2 * lq] = make_float2(xo0, xo1);           \
      *(float2*)&Xs[q][(J) + 1][2 * lq] = make_float2(xo0, xo1);          \
    }

    float4 a0, a1, a2, a3, e0, e1, e2, e3;
    float2 dA, dE;
    CLOAD(0, a0, a1, a2, a3, dA);
    CLOAD(1, e0, e1, e2, e3, dE);
    #pragma unroll
    for (int j = 0; j < NJ; j += 2) {
      TSTEP(a0, a1, a2, a3, dA, j);
      if (j + 2 < NJ) CLOAD(j + 2, a0, a1, a2, a3, dA);
      TSTEP(e0, e1, e2, e3, dE, j + 1);
      if (j + 3 < NJ) CLOAD(j + 3, e0, e1, e2, e3, dE);
    }
#undef CLOAD
#undef TSTEP
  }

  __syncthreads();

  {  // ---------------- post phase: even outputs ----------------
    const int j = t >> 4, q = (t >> 3) & 1, r = t & 7;
    const int ia = i_first + 2 * j;
    if (ia >= o_lo && ia < o_hi) {
      const int s_e = 4 * j + q;
      const int te = 4 * s_e + (r >> 1);
      const int he = 2 * (r & 1);
      const float4 xlo = *(const float4*)&Xs[q][j][0];
      const float4 xhi = *(const float4*)&Xs[q][j][4];
      const float4 clo = *(const float4*)((const char*)Cs + (((he    ) * THREADS + te) * 16));
      const float4 chi = *(const float4*)((const char*)Cs + (((he + 1) * THREADS + te) * 16));
      float acc = Ds[te * 2 + (r & 1)];
      acc = fmaf(-clo.x, xlo.x, acc);
      acc = fmaf(-clo.y, xlo.y, acc);
      acc = fmaf(-clo.z, xlo.z, acc);
      acc = fmaf(-clo.w, xlo.w, acc);
      acc = fmaf(-chi.x, xhi.x, acc);
      acc = fmaf(-chi.y, xhi.y, acc);
      acc = fmaf(-chi.z, xhi.z, acc);
      acc = fmaf(-chi.w, xhi.w, acc);
      out[(long)(b0 + q) * (NBLK * SBLK) + ia * 8 + r] = acc;
    }
  }
}

extern "C" void kernel_launch(void* const* d_in, const int* in_sizes, int n_in,
                              void* d_out, int out_size, void* d_ws, size_t ws_size,
                              hipStream_t stream) {
  const float* A = (const float*)d_in[0];
  const float* B = (const float*)d_in[1];
  const float* v = (const float*)d_in[2];
  float* out = (float*)d_out;

  pcr_fused<<<NCH * (SBAT / P), THREADS, 0, stream>>>(A, B, v, out);
}